// Round 1
// baseline (621.434 us; speedup 1.0000x reference)
//
#include <hip/hip_runtime.h>

#define N_PTS 400000
#define EPS 1e-5f

typedef __attribute__((ext_vector_type(8))) short short8;
typedef __attribute__((ext_vector_type(4))) float f32x4;

// ws layout (bytes)
constexpr size_t H_OFF   = 0;                       // h bf16 [N][64]  = 51,200,000 B
constexpr size_t W1T_OFF = 51200000;                // w1t bf16 [64][128] = 16,384 B
constexpr size_t W2T_OFF = W1T_OFF + 16384;         // w2t bf16 [27][64][64] = 221,184 B
constexpr size_t W3T_OFF = W2T_OFF + 221184;        // w3t bf16 [128][64] = 16,384 B
constexpr size_t BNC_OFF = W3T_OFF + 16384;         // 512 f32 = 2,048 B

__device__ __forceinline__ short f2bf(float f) {
  unsigned u = __builtin_bit_cast(unsigned, f);
  u += 0x7FFFu + ((u >> 16) & 1u);   // RNE
  return (short)(u >> 16);
}

// ---------------- prep: weight transpose/convert + BN folding ----------------
__global__ __launch_bounds__(256) void prep_kernel(
    const float* __restrict__ w1, const float* __restrict__ w2,
    const float* __restrict__ w3,
    const float* __restrict__ g1, const float* __restrict__ b1,
    const float* __restrict__ m1, const float* __restrict__ v1,
    const float* __restrict__ g2, const float* __restrict__ b2,
    const float* __restrict__ m2, const float* __restrict__ v2,
    const float* __restrict__ g3, const float* __restrict__ b3,
    const float* __restrict__ m3, const float* __restrict__ v3,
    short* __restrict__ w1t, short* __restrict__ w2t,
    short* __restrict__ w3t, float* __restrict__ bnc) {
  int tid = blockIdx.x * 256 + threadIdx.x;
  int gs = gridDim.x * 256;
  for (int i = tid; i < 128 * 64; i += gs) {        // w1[k][n] -> w1t[n][k]
    int k = i >> 6, n = i & 63;
    w1t[n * 128 + k] = f2bf(w1[i]);
  }
  for (int i = tid; i < 27 * 64 * 64; i += gs) {    // w2[kk][k][n] -> w2t[kk][n][k]
    int kk = i >> 12, r = i & 4095, k = r >> 6, n = r & 63;
    w2t[kk * 4096 + n * 64 + k] = f2bf(w2[i]);
  }
  for (int i = tid; i < 64 * 128; i += gs) {        // w3[k][n] -> w3t[n][k]
    int k = i >> 7, n = i & 127;
    w3t[n * 64 + k] = f2bf(w3[i]);
  }
  if (tid < 64) {
    float s = g1[tid] * rsqrtf(v1[tid] + EPS);
    bnc[tid] = s; bnc[64 + tid] = b1[tid] - m1[tid] * s;
  } else if (tid < 128) {
    int c = tid - 64;
    float s = g2[c] * rsqrtf(v2[c] + EPS);
    bnc[128 + c] = s; bnc[192 + c] = b2[c] - m2[c] * s;
  } else if (tid < 256) {
    int c = tid - 128;
    float s = g3[c] * rsqrtf(v3[c] + EPS);
    bnc[256 + c] = s; bnc[384 + c] = b3[c] - m3[c] * s;
  }
}

// ---------------- stage 1: h = relu(bn1(x @ w1)), bf16 out ----------------
// wave = 64 rows (4 m-tiles of 16). MFMA 16x16x32 bf16, K=128 (4 K-steps).
__global__ __launch_bounds__(256) void stage1_kernel(
    const float* __restrict__ x, const short* __restrict__ w1t,
    const float* __restrict__ bnc, short* __restrict__ h) {
  const int lane = threadIdx.x & 63;
  const int wid = threadIdx.x >> 6;
  const int lr = lane & 15, lk = lane >> 4;
  const long wbase = ((long)blockIdx.x * 4 + wid) * 64;
  if (wbase >= N_PTS) return;

  short8 bf[4][4];
#pragma unroll
  for (int nf = 0; nf < 4; ++nf)
#pragma unroll
    for (int ks = 0; ks < 4; ++ks)
      bf[nf][ks] = *(const short8*)(w1t + (nf * 16 + lr) * 128 + ks * 32 + lk * 8);

  float s[4], t[4];
#pragma unroll
  for (int nf = 0; nf < 4; ++nf) {
    int ch = nf * 16 + lr;
    s[nf] = bnc[ch]; t[nf] = bnc[64 + ch];
  }

#pragma unroll
  for (int mt = 0; mt < 4; ++mt) {
    f32x4 acc[4];
#pragma unroll
    for (int nf = 0; nf < 4; ++nf) acc[nf] = f32x4{0.f, 0.f, 0.f, 0.f};
    const float* xr = x + (wbase + mt * 16 + lr) * 128 + lk * 8;
#pragma unroll
    for (int ks = 0; ks < 4; ++ks) {
      f32x4 lo = *(const f32x4*)(xr + ks * 32);
      f32x4 hi = *(const f32x4*)(xr + ks * 32 + 4);
      short8 a;
#pragma unroll
      for (int j = 0; j < 4; ++j) { a[j] = f2bf(lo[j]); a[4 + j] = f2bf(hi[j]); }
#pragma unroll
      for (int nf = 0; nf < 4; ++nf)
        acc[nf] = __builtin_amdgcn_mfma_f32_16x16x32_bf16(a, bf[nf][ks], acc[nf], 0, 0, 0);
    }
    short* hr = h + (wbase + mt * 16) * 64;
#pragma unroll
    for (int nf = 0; nf < 4; ++nf) {
      int ch = nf * 16 + lr;
#pragma unroll
      for (int j = 0; j < 4; ++j) {
        int row = lk * 4 + j;
        float v = acc[nf][j] * s[nf] + t[nf];
        v = v > 0.f ? v : 0.f;
        hr[row * 64 + ch] = f2bf(v);
      }
    }
  }
}

// ------- stage 2+3: h2 = relu(bn2(sum_k h[nb[k]]@w2[k])); out = relu(bn3(h2@w3)+x)
// wave = 64 rows (4 m-tiles). Gathered A-fragments loaded straight from global.
__global__ __launch_bounds__(256) void stage23_kernel(
    const short* __restrict__ h, const int* __restrict__ nb,
    const short* __restrict__ w2t, const short* __restrict__ w3t,
    const float* __restrict__ bnc, const float* __restrict__ x,
    float* __restrict__ out) {
  __shared__ __align__(16) short lds[4][16][72];   // per-wave 16x64 tile, stride 72 to spread banks
  const int lane = threadIdx.x & 63;
  const int wid = threadIdx.x >> 6;
  const int lr = lane & 15, lk = lane >> 4;
  const long wbase = ((long)blockIdx.x * 4 + wid) * 64;
  if (wbase >= N_PTS) return;

  f32x4 acc[4][4];
#pragma unroll
  for (int mt = 0; mt < 4; ++mt)
#pragma unroll
    for (int nf = 0; nf < 4; ++nf) acc[mt][nf] = f32x4{0.f, 0.f, 0.f, 0.f};

  for (int k = 0; k < 27; ++k) {
    const int* nbk = nb + (long)k * N_PTS + wbase;
    const short* w2k = w2t + k * 4096;
    int idx[4];
#pragma unroll
    for (int mt = 0; mt < 4; ++mt) idx[mt] = nbk[mt * 16 + lr];
    short8 a[4][2], b[4][2];
#pragma unroll
    for (int ks = 0; ks < 2; ++ks) {
#pragma unroll
      for (int nf = 0; nf < 4; ++nf)
        b[nf][ks] = *(const short8*)(w2k + (nf * 16 + lr) * 64 + ks * 32 + lk * 8);
#pragma unroll
      for (int mt = 0; mt < 4; ++mt)
        a[mt][ks] = *(const short8*)(h + (long)idx[mt] * 64 + ks * 32 + lk * 8);
    }
#pragma unroll
    for (int mt = 0; mt < 4; ++mt)
#pragma unroll
      for (int nf = 0; nf < 4; ++nf)
#pragma unroll
        for (int ks = 0; ks < 2; ++ks)
          acc[mt][nf] = __builtin_amdgcn_mfma_f32_16x16x32_bf16(a[mt][ks], b[nf][ks], acc[mt][nf], 0, 0, 0);
  }

  // bn2 scale/shift + bn3 scale/shift hoisted
  float s2[4], t2[4];
#pragma unroll
  for (int nf = 0; nf < 4; ++nf) {
    int ch = nf * 16 + lr;
    s2[nf] = bnc[128 + ch]; t2[nf] = bnc[192 + ch];
  }

#pragma unroll
  for (int mt = 0; mt < 4; ++mt) {
    // C-layout -> LDS (bf16) in row-major [16][64] (stride 72)
#pragma unroll
    for (int nf = 0; nf < 4; ++nf) {
      int ch = nf * 16 + lr;
#pragma unroll
      for (int j = 0; j < 4; ++j) {
        float v = acc[mt][nf][j] * s2[nf] + t2[nf];
        v = v > 0.f ? v : 0.f;
        lds[wid][lk * 4 + j][ch] = f2bf(v);
      }
    }
    asm volatile("s_waitcnt lgkmcnt(0)" ::: "memory");
    __builtin_amdgcn_sched_barrier(0);

    // stage 3: A from LDS (A-layout), B = w3t from global (L1-resident, 16 KB)
    f32x4 acc3[8];
#pragma unroll
    for (int nf = 0; nf < 8; ++nf) acc3[nf] = f32x4{0.f, 0.f, 0.f, 0.f};
#pragma unroll
    for (int ks = 0; ks < 2; ++ks) {
      short8 a3 = *(const short8*)&lds[wid][lr][ks * 32 + lk * 8];
#pragma unroll
      for (int nf = 0; nf < 8; ++nf) {
        short8 b3 = *(const short8*)(w3t + (nf * 16 + lr) * 64 + ks * 32 + lk * 8);
        acc3[nf] = __builtin_amdgcn_mfma_f32_16x16x32_bf16(a3, b3, acc3[nf], 0, 0, 0);
      }
    }
    __builtin_amdgcn_sched_barrier(0);

    // epilogue: bn3 + residual + relu, f32 out
    const float* xr = x + (wbase + mt * 16 + lk * 4) * 128;
    float* outr = out + (wbase + mt * 16 + lk * 4) * 128;
#pragma unroll
    for (int nf = 0; nf < 8; ++nf) {
      int ch = nf * 16 + lr;
      float s3 = bnc[256 + ch], t3 = bnc[384 + ch];
#pragma unroll
      for (int j = 0; j < 4; ++j) {
        float v = acc3[nf][j] * s3 + t3 + xr[j * 128 + ch];
        outr[j * 128 + ch] = v > 0.f ? v : 0.f;
      }
    }
    __builtin_amdgcn_sched_barrier(0);
  }
}

extern "C" void kernel_launch(void* const* d_in, const int* in_sizes, int n_in,
                              void* d_out, int out_size, void* d_ws, size_t ws_size,
                              hipStream_t stream) {
  const float* x  = (const float*)d_in[0];
  const int*   nb = (const int*)d_in[1];
  const float* w1 = (const float*)d_in[2];
  const float* w2 = (const float*)d_in[3];
  const float* w3 = (const float*)d_in[4];
  const float* g1 = (const float*)d_in[5];
  const float* b1 = (const float*)d_in[6];
  const float* m1 = (const float*)d_in[7];
  const float* v1 = (const float*)d_in[8];
  const float* g2 = (const float*)d_in[9];
  const float* b2 = (const float*)d_in[10];
  const float* m2 = (const float*)d_in[11];
  const float* v2 = (const float*)d_in[12];
  const float* g3 = (const float*)d_in[13];
  const float* b3 = (const float*)d_in[14];
  const float* m3 = (const float*)d_in[15];
  const float* v3 = (const float*)d_in[16];

  char* ws = (char*)d_ws;
  short* hbuf = (short*)(ws + H_OFF);
  short* w1t  = (short*)(ws + W1T_OFF);
  short* w2t  = (short*)(ws + W2T_OFF);
  short* w3t  = (short*)(ws + W3T_OFF);
  float* bnc  = (float*)(ws + BNC_OFF);
  float* outp = (float*)d_out;

  prep_kernel<<<128, 256, 0, stream>>>(w1, w2, w3,
                                       g1, b1, m1, v1,
                                       g2, b2, m2, v2,
                                       g3, b3, m3, v3,
                                       w1t, w2t, w3t, bnc);
  stage1_kernel<<<1563, 256, 0, stream>>>(x, w1t, bnc, hbuf);
  stage23_kernel<<<1563, 256, 0, stream>>>(hbuf, nb, w2t, w3t, bnc, x, outp);
}

// Round 2
// 375.477 us; speedup vs baseline: 1.6551x; 1.6551x over previous
//
#include <hip/hip_runtime.h>

#define N_PTS 400000
#define EPS 1e-5f

typedef __attribute__((ext_vector_type(8))) short short8;
typedef __attribute__((ext_vector_type(4))) float f32x4;

// ws layout (bytes)
constexpr size_t H_OFF   = 0;                       // h bf16 [N][64]  = 51,200,000 B
constexpr size_t W1T_OFF = 51200000;                // w1t bf16 [64][128] = 16,384 B
constexpr size_t W2S_OFF = W1T_OFF + 16384;         // w2s bf16 [27][4096] (swizzled) = 221,184 B
constexpr size_t W3T_OFF = W2S_OFF + 221184;        // w3t bf16 [128][64] = 16,384 B
constexpr size_t BNC_OFF = W3T_OFF + 16384;         // 512 f32 = 2,048 B

__device__ __forceinline__ short f2bf(float f) {
  unsigned u = __builtin_bit_cast(unsigned, f);
  u += 0x7FFFu + ((u >> 16) & 1u);   // RNE
  return (short)(u >> 16);
}

// ---------------- prep: weight transpose/convert + BN folding ----------------
__global__ __launch_bounds__(256) void prep_kernel(
    const float* __restrict__ w1, const float* __restrict__ w2,
    const float* __restrict__ w3,
    const float* __restrict__ g1, const float* __restrict__ b1,
    const float* __restrict__ m1, const float* __restrict__ v1,
    const float* __restrict__ g2, const float* __restrict__ b2,
    const float* __restrict__ m2, const float* __restrict__ v2,
    const float* __restrict__ g3, const float* __restrict__ b3,
    const float* __restrict__ m3, const float* __restrict__ v3,
    short* __restrict__ w1t, short* __restrict__ w2s,
    short* __restrict__ w3t, float* __restrict__ bnc) {
  int tid = blockIdx.x * 256 + threadIdx.x;
  int gs = gridDim.x * 256;
  for (int i = tid; i < 128 * 64; i += gs) {        // w1[k][n] -> w1t[n][k]
    int k = i >> 6, n = i & 63;
    w1t[n * 128 + k] = f2bf(w1[i]);
  }
  for (int i = tid; i < 27 * 64 * 64; i += gs) {    // w2[kk][k][n] -> swizzled w2s[kk][n][k]
    int kk = i >> 12, r = i & 4095, k = r >> 6, n = r & 63;
    int byte = (n * 64 + k) * 2;
    byte ^= (n & 7) << 4;                            // st-style XOR swizzle (involution)
    w2s[kk * 4096 + (byte >> 1)] = f2bf(w2[i]);
  }
  for (int i = tid; i < 64 * 128; i += gs) {        // w3[k][n] -> w3t[n][k]
    int k = i >> 7, n = i & 127;
    w3t[n * 64 + k] = f2bf(w3[i]);
  }
  if (tid < 64) {
    float s = g1[tid] * rsqrtf(v1[tid] + EPS);
    bnc[tid] = s; bnc[64 + tid] = b1[tid] - m1[tid] * s;
  } else if (tid < 128) {
    int c = tid - 64;
    float s = g2[c] * rsqrtf(v2[c] + EPS);
    bnc[128 + c] = s; bnc[192 + c] = b2[c] - m2[c] * s;
  } else if (tid < 256) {
    int c = tid - 128;
    float s = g3[c] * rsqrtf(v3[c] + EPS);
    bnc[256 + c] = s; bnc[384 + c] = b3[c] - m3[c] * s;
  }
}

// ---------------- stage 1: h = relu(bn1(x @ w1)), bf16 out ----------------
__global__ __launch_bounds__(256) void stage1_kernel(
    const float* __restrict__ x, const short* __restrict__ w1t,
    const float* __restrict__ bnc, short* __restrict__ h) {
  const int lane = threadIdx.x & 63;
  const int wid = threadIdx.x >> 6;
  const int lr = lane & 15, lk = lane >> 4;
  const long wbase = ((long)blockIdx.x * 4 + wid) * 64;
  if (wbase >= N_PTS) return;

  short8 bf[4][4];
#pragma unroll
  for (int nf = 0; nf < 4; ++nf)
#pragma unroll
    for (int ks = 0; ks < 4; ++ks)
      bf[nf][ks] = *(const short8*)(w1t + (nf * 16 + lr) * 128 + ks * 32 + lk * 8);

  float s[4], t[4];
#pragma unroll
  for (int nf = 0; nf < 4; ++nf) {
    int ch = nf * 16 + lr;
    s[nf] = bnc[ch]; t[nf] = bnc[64 + ch];
  }

#pragma unroll
  for (int mt = 0; mt < 4; ++mt) {
    f32x4 acc[4];
#pragma unroll
    for (int nf = 0; nf < 4; ++nf) acc[nf] = f32x4{0.f, 0.f, 0.f, 0.f};
    const float* xr = x + (wbase + mt * 16 + lr) * 128 + lk * 8;
#pragma unroll
    for (int ks = 0; ks < 4; ++ks) {
      f32x4 lo = *(const f32x4*)(xr + ks * 32);
      f32x4 hi = *(const f32x4*)(xr + ks * 32 + 4);
      short8 a;
#pragma unroll
      for (int j = 0; j < 4; ++j) { a[j] = f2bf(lo[j]); a[4 + j] = f2bf(hi[j]); }
#pragma unroll
      for (int nf = 0; nf < 4; ++nf)
        acc[nf] = __builtin_amdgcn_mfma_f32_16x16x32_bf16(a, bf[nf][ks], acc[nf], 0, 0, 0);
    }
    short* hr = h + (wbase + mt * 16) * 64;
#pragma unroll
    for (int nf = 0; nf < 4; ++nf) {
      int ch = nf * 16 + lr;
#pragma unroll
      for (int j = 0; j < 4; ++j) {
        int row = lk * 4 + j;
        float v = acc[nf][j] * s[nf] + t[nf];
        v = v > 0.f ? v : 0.f;
        hr[row * 64 + ch] = f2bf(v);
      }
    }
  }
}

// ------- stage 2+3 (pipelined): h2 = relu(bn2(sum_k h[nb[k]]@w2[k])); out = relu(bn3(h2@w3)+x)
// wave = 32 rows (2 m-tiles). idx prefetch depth 3, gather prefetch depth 1,
// B double-buffered in LDS (staged 2 iters ahead), one raw s_barrier per k.
__global__ __launch_bounds__(256, 4) void stage23_kernel(
    const short* __restrict__ h, const int* __restrict__ nb,
    const short* __restrict__ w2s, const short* __restrict__ w3t,
    const float* __restrict__ bnc, const float* __restrict__ x,
    float* __restrict__ out) {
  __shared__ __align__(16) short bbuf[2][4096];      // 16 KB double-buffered B
  __shared__ __align__(16) short tile[4][16][72];    // per-wave stage-3 reshape tile
  const int tid = threadIdx.x;
  const int lane = tid & 63;
  const int wid = tid >> 6;
  const int lr = lane & 15, lk = lane >> 4;
  const long wbase = ((long)blockIdx.x * 4 + wid) * 32;

  // swizzled LDS short-offsets for the 8 B-fragments
  int boff[4][2];
#pragma unroll
  for (int nf = 0; nf < 4; ++nf) {
    int row = nf * 16 + lr;
#pragma unroll
    for (int ks = 0; ks < 2; ++ks)
      boff[nf][ks] = ((row * 128 + ks * 64 + lk * 16) ^ ((row & 7) << 4)) >> 1;
  }

  f32x4 acc[2][4];
#pragma unroll
  for (int mt = 0; mt < 2; ++mt)
#pragma unroll
    for (int nf = 0; nf < 4; ++nf) acc[mt][nf] = f32x4{0.f, 0.f, 0.f, 0.f};

  // ---- prologue: idx(0..2), gather(0), stage B(0),B(1) ----
  int idxq[4][2];
#pragma unroll
  for (int kk = 0; kk < 3; ++kk)
#pragma unroll
    for (int mt = 0; mt < 2; ++mt)
      idxq[kk][mt] = nb[(long)kk * N_PTS + wbase + mt * 16 + lr];

  short8 acur[2][2], anext[2][2];
#pragma unroll
  for (int mt = 0; mt < 2; ++mt)
#pragma unroll
    for (int ks = 0; ks < 2; ++ks)
      acur[mt][ks] = *(const short8*)(h + (long)idxq[0][mt] * 64 + ks * 32 + lk * 8);

  {
    short8 b0a = *(const short8*)(w2s + tid * 16);
    short8 b0b = *(const short8*)(w2s + tid * 16 + 8);
    short8 b1a = *(const short8*)(w2s + 4096 + tid * 16);
    short8 b1b = *(const short8*)(w2s + 4096 + tid * 16 + 8);
    *(short8*)(&bbuf[0][tid * 16]) = b0a;
    *(short8*)(&bbuf[0][tid * 16 + 8]) = b0b;
    *(short8*)(&bbuf[1][tid * 16]) = b1a;
    *(short8*)(&bbuf[1][tid * 16 + 8]) = b1b;
  }
  asm volatile("s_waitcnt lgkmcnt(0)" ::: "memory");
  __builtin_amdgcn_s_barrier();

  // ---- main k-loop (fully unrolled; all queue indices compile-time) ----
#pragma unroll
  for (int k = 0; k < 27; ++k) {
    const int kp = k & 1;
    short8 bsa, bsb;
    if (k + 2 < 27) {               // B loads for k+2 (written to LDS at step5)
      bsa = *(const short8*)(w2s + (k + 2) * 4096 + tid * 16);
      bsb = *(const short8*)(w2s + (k + 2) * 4096 + tid * 16 + 8);
    }
    if (k + 3 < 27) {               // idx loads for k+3 (depth-3 prefetch)
#pragma unroll
      for (int mt = 0; mt < 2; ++mt)
        idxq[(k + 3) & 3][mt] = nb[(long)(k + 3) * N_PTS + wbase + mt * 16 + lr];
    }
    if (k + 1 < 27) {               // gathers for k+1 (depth-1 prefetch)
#pragma unroll
      for (int mt = 0; mt < 2; ++mt)
#pragma unroll
        for (int ks = 0; ks < 2; ++ks)
          anext[mt][ks] = *(const short8*)(h + (long)idxq[(k + 1) & 3][mt] * 64 + ks * 32 + lk * 8);
    }
    // MFMA on current k: B from LDS (swizzled, conflict-free)
#pragma unroll
    for (int nf = 0; nf < 4; ++nf) {
#pragma unroll
      for (int ks = 0; ks < 2; ++ks) {
        short8 bf = *(const short8*)(&bbuf[kp][boff[nf][ks]]);
#pragma unroll
        for (int mt = 0; mt < 2; ++mt)
          acc[mt][nf] = __builtin_amdgcn_mfma_f32_16x16x32_bf16(acur[mt][ks], bf, acc[mt][nf], 0, 0, 0);
      }
    }
    asm volatile("s_waitcnt lgkmcnt(0)" ::: "memory");
    __builtin_amdgcn_s_barrier();
    if (k + 2 < 27) {               // write staged B into the buffer just freed
      *(short8*)(&bbuf[kp][tid * 16]) = bsa;
      *(short8*)(&bbuf[kp][tid * 16 + 8]) = bsb;
    }
    if (k + 1 < 27) {
#pragma unroll
      for (int mt = 0; mt < 2; ++mt)
#pragma unroll
        for (int ks = 0; ks < 2; ++ks)
          acur[mt][ks] = anext[mt][ks];
    }
  }

  // ---- stage 3 + epilogue ----
  float s2[4], t2[4];
#pragma unroll
  for (int nf = 0; nf < 4; ++nf) {
    int ch = nf * 16 + lr;
    s2[nf] = bnc[128 + ch]; t2[nf] = bnc[192 + ch];
  }

#pragma unroll
  for (int mt = 0; mt < 2; ++mt) {
#pragma unroll
    for (int nf = 0; nf < 4; ++nf) {
      int ch = nf * 16 + lr;
#pragma unroll
      for (int j = 0; j < 4; ++j) {
        float v = acc[mt][nf][j] * s2[nf] + t2[nf];
        v = v > 0.f ? v : 0.f;
        tile[wid][lk * 4 + j][ch] = f2bf(v);
      }
    }
    asm volatile("s_waitcnt lgkmcnt(0)" ::: "memory");
    __builtin_amdgcn_sched_barrier(0);

    f32x4 acc3[8];
#pragma unroll
    for (int nf = 0; nf < 8; ++nf) acc3[nf] = f32x4{0.f, 0.f, 0.f, 0.f};
#pragma unroll
    for (int ks = 0; ks < 2; ++ks) {
      short8 a3 = *(const short8*)&tile[wid][lr][ks * 32 + lk * 8];
#pragma unroll
      for (int nf = 0; nf < 8; ++nf) {
        short8 b3 = *(const short8*)(w3t + (nf * 16 + lr) * 64 + ks * 32 + lk * 8);
        acc3[nf] = __builtin_amdgcn_mfma_f32_16x16x32_bf16(a3, b3, acc3[nf], 0, 0, 0);
      }
    }
    __builtin_amdgcn_sched_barrier(0);

    const float* xr = x + (wbase + mt * 16 + lk * 4) * 128;
    float* outr = out + (wbase + mt * 16 + lk * 4) * 128;
#pragma unroll
    for (int nf = 0; nf < 8; ++nf) {
      int ch = nf * 16 + lr;
      float s3 = bnc[256 + ch], t3 = bnc[384 + ch];
#pragma unroll
      for (int j = 0; j < 4; ++j) {
        float v = acc3[nf][j] * s3 + t3 + xr[j * 128 + ch];
        outr[j * 128 + ch] = v > 0.f ? v : 0.f;
      }
    }
    __builtin_amdgcn_sched_barrier(0);
  }
}

extern "C" void kernel_launch(void* const* d_in, const int* in_sizes, int n_in,
                              void* d_out, int out_size, void* d_ws, size_t ws_size,
                              hipStream_t stream) {
  const float* x  = (const float*)d_in[0];
  const int*   nb = (const int*)d_in[1];
  const float* w1 = (const float*)d_in[2];
  const float* w2 = (const float*)d_in[3];
  const float* w3 = (const float*)d_in[4];
  const float* g1 = (const float*)d_in[5];
  const float* b1 = (const float*)d_in[6];
  const float* m1 = (const float*)d_in[7];
  const float* v1 = (const float*)d_in[8];
  const float* g2 = (const float*)d_in[9];
  const float* b2 = (const float*)d_in[10];
  const float* m2 = (const float*)d_in[11];
  const float* v2 = (const float*)d_in[12];
  const float* g3 = (const float*)d_in[13];
  const float* b3 = (const float*)d_in[14];
  const float* m3 = (const float*)d_in[15];
  const float* v3 = (const float*)d_in[16];

  char* ws = (char*)d_ws;
  short* hbuf = (short*)(ws + H_OFF);
  short* w1t  = (short*)(ws + W1T_OFF);
  short* w2s  = (short*)(ws + W2S_OFF);
  short* w3t  = (short*)(ws + W3T_OFF);
  float* bnc  = (float*)(ws + BNC_OFF);
  float* outp = (float*)d_out;

  prep_kernel<<<128, 256, 0, stream>>>(w1, w2, w3,
                                       g1, b1, m1, v1,
                                       g2, b2, m2, v2,
                                       g3, b3, m3, v3,
                                       w1t, w2s, w3t, bnc);
  stage1_kernel<<<1563, 256, 0, stream>>>(x, w1t, bnc, hbuf);
  stage23_kernel<<<3125, 256, 0, stream>>>(hbuf, nb, w2s, w3t, bnc, x, outp);
}